// Round 3
// baseline (1097.838 us; speedup 1.0000x reference)
//
#include <hip/hip_runtime.h>

#define D 128
#define RSQRT_D 0.088388347648318440550f  // 1/sqrt(128)
#define NEG_HUGE -3.4e38f

// ============================ CSR build ============================

__global__ void hist_kernel(const int* __restrict__ recv, int* __restrict__ cnt, int E) {
    int e = blockIdx.x * blockDim.x + threadIdx.x;
    if (e >= E) return;
    atomicAdd(&cnt[recv[e]], 1);
}

#define SCAN_B 256
__global__ void scan1_kernel(const int* __restrict__ cnt, int* __restrict__ excl,
                             int* __restrict__ bsum, int N) {
    __shared__ int tmp[SCAN_B];
    int i = blockIdx.x * SCAN_B + threadIdx.x;
    int v = (i < N) ? cnt[i] : 0;
    tmp[threadIdx.x] = v;
    __syncthreads();
#pragma unroll
    for (int off = 1; off < SCAN_B; off <<= 1) {
        int t = (threadIdx.x >= off) ? tmp[threadIdx.x - off] : 0;
        __syncthreads();
        tmp[threadIdx.x] += t;
        __syncthreads();
    }
    if (i < N) excl[i] = tmp[threadIdx.x] - v;
    if (threadIdx.x == SCAN_B - 1) bsum[blockIdx.x] = tmp[threadIdx.x];
}

__global__ void scan2_kernel(int* __restrict__ bsum, int nb) {
    __shared__ int tmp[SCAN_B];
    int v = (threadIdx.x < nb) ? bsum[threadIdx.x] : 0;
    tmp[threadIdx.x] = v;
    __syncthreads();
#pragma unroll
    for (int off = 1; off < SCAN_B; off <<= 1) {
        int t = (threadIdx.x >= off) ? tmp[threadIdx.x - off] : 0;
        __syncthreads();
        tmp[threadIdx.x] += t;
        __syncthreads();
    }
    if (threadIdx.x < nb) bsum[threadIdx.x] = tmp[threadIdx.x] - v;
}

__global__ void scan3_kernel(const int* __restrict__ excl, const int* __restrict__ bsum,
                             int* __restrict__ start, int N, int E) {
    int i = blockIdx.x * SCAN_B + threadIdx.x;
    if (i < N) start[i] = excl[i] + bsum[blockIdx.x];
    if (i == N) start[N] = E;
}

__global__ void fill_kernel(const int* __restrict__ recv, const int* __restrict__ start,
                            int* __restrict__ cursor, int* __restrict__ eidx, int E) {
    int e = blockIdx.x * blockDim.x + threadIdx.x;
    if (e >= E) return;
    int r = recv[e];
    int p = atomicAdd(&cursor[r], 1);
    eidx[start[r] + p] = e;
}

// ============================ weight folds (packed float4 layout) ============================
// Packed layout P: for element (row i, col j):
//   P[((i>>1)*64 + (j>>1))*4 + (i&1)*2 + (j&1)]
// so a float4 at [i64*64 + l] holds rows {2*i64,2*i64+1} x cols {2l,2l+1}.

__global__ void fold_wvo_kernel(const float* __restrict__ Wv, const float* __restrict__ Wo,
                                const float* __restrict__ bv,
                                float* __restrict__ Pvo, float* __restrict__ bvo) {
    int j = threadIdx.x;
    int i = blockIdx.x;
    if (i < D) {
        float acc = 0.f;
        for (int t = 0; t < D; ++t) acc += Wv[(size_t)i * D + t] * Wo[(size_t)t * D + j];
        Pvo[(((i >> 1) * 64 + (j >> 1)) << 2) + ((i & 1) << 1) + (j & 1)] = acc;
    } else {
        float acc = 0.f;
        for (int t = 0; t < D; ++t) acc += bv[t] * Wo[(size_t)t * D + j];
        bvo[j] = acc;
    }
}

// Wqk[i][j] = sum_t Wq[i][t]*Wk[j][t] (packed); bqk[j] = sum_t bq[t]*Wk[j][t];
// wqb[j] = sum_t Wq[j][t]*bk[t]; bqb = bq.bk
__global__ void fold_wqk_kernel(const float* __restrict__ Wq, const float* __restrict__ Wk,
                                const float* __restrict__ bq, const float* __restrict__ bk,
                                float* __restrict__ Pqk, float* __restrict__ bqk,
                                float* __restrict__ wqb, float* __restrict__ bqb) {
    int j = threadIdx.x;
    int i = blockIdx.x;
    if (i < D) {
        float acc = 0.f;
        for (int t = 0; t < D; ++t) acc += Wq[(size_t)i * D + t] * Wk[(size_t)j * D + t];
        Pqk[(((i >> 1) * 64 + (j >> 1)) << 2) + ((i & 1) << 1) + (j & 1)] = acc;
    } else {
        float a1 = 0.f, a2 = 0.f;
        for (int t = 0; t < D; ++t) {
            a1 += bq[t] * Wk[(size_t)j * D + t];
            a2 += Wq[(size_t)j * D + t] * bk[t];
        }
        bqk[j] = a1;
        wqb[j] = a2;
        if (j == 0) {
            float b = 0.f;
            for (int t = 0; t < D; ++t) b += bq[t] * bk[t];
            *bqb = b;
        }
    }
}

// ============================ fused per-node kernel ============================

__device__ __forceinline__ float wave_sum(float v) {
#pragma unroll
    for (int off = 1; off < 64; off <<= 1) v += __shfl_xor(v, off);
    return v;
}

__device__ __forceinline__ float rdlane(float v, int l) {
    return __uint_as_float(__builtin_amdgcn_readlane(__float_as_uint(v), l));
}

#define NB 4  // nodes per wave

__global__ __launch_bounds__(256) void fused_kernel(
        const float* __restrict__ msg, const int* __restrict__ eidx,
        const int* __restrict__ start,
        const float* __restrict__ Pqk, const float* __restrict__ bqk,
        const float* __restrict__ wqb, const float* __restrict__ bqbp,
        const float* __restrict__ Pvo, const float* __restrict__ bvo,
        const float* __restrict__ bo,
        float* __restrict__ out, int N) {
    int lane = threadIdx.x & 63;
    int wid = blockIdx.x * (blockDim.x >> 6) + (threadIdx.x >> 6);
    int n0 = wid * NB;
    if (n0 >= N) return;

    int s0[NB], s1[NB];
    float2 sum[NB];

    // ---- pass A: per-node edge sums (4-deep load batching) ----
#pragma unroll
    for (int b = 0; b < NB; ++b) {
        int n = n0 + b;
        s0[b] = (n < N) ? start[n] : 0;
        s1[b] = (n < N) ? start[n + 1] : 0;
        float2 a0 = {0.f, 0.f}, a1 = {0.f, 0.f}, a2 = {0.f, 0.f}, a3 = {0.f, 0.f};
        int j = s0[b];
        for (; j + 4 <= s1[b]; j += 4) {
            int e0 = eidx[j], e1 = eidx[j + 1], e2 = eidx[j + 2], e3 = eidx[j + 3];
            float2 r0 = ((const float2*)(msg + (size_t)e0 * D))[lane];
            float2 r1 = ((const float2*)(msg + (size_t)e1 * D))[lane];
            float2 r2 = ((const float2*)(msg + (size_t)e2 * D))[lane];
            float2 r3 = ((const float2*)(msg + (size_t)e3 * D))[lane];
            a0.x += r0.x; a0.y += r0.y;
            a1.x += r1.x; a1.y += r1.y;
            a2.x += r2.x; a2.y += r2.y;
            a3.x += r3.x; a3.y += r3.y;
        }
        for (; j < s1[b]; ++j) {
            int e = eidx[j];
            float2 r = ((const float2*)(msg + (size_t)e * D))[lane];
            a0.x += r.x; a0.y += r.y;
        }
        sum[b].x = (a0.x + a1.x) + (a2.x + a3.x);
        sum[b].y = (a0.y + a1.y) + (a2.y + a3.y);
    }

    // ---- qb[b] = sum . wqb + bqb ----
    float2 wq = ((const float2*)wqb)[lane];
    float bqb = bqbp[0];
    float qb[NB];
#pragma unroll
    for (int b = 0; b < NB; ++b)
        qb[b] = wave_sum(sum[b].x * wq.x + sum[b].y * wq.y) + bqb;

    // ---- qk[b] = sum @ Wqk + bqk (packed matvec, readlane broadcast) ----
    float2 bq2 = ((const float2*)bqk)[lane];
    float2 qk[NB];
#pragma unroll
    for (int b = 0; b < NB; ++b) qk[b] = bq2;
    const float4* P4 = (const float4*)Pqk;
#pragma unroll
    for (int i = 0; i < 64; ++i) {
        float4 w = P4[i * 64 + lane];
#pragma unroll
        for (int b = 0; b < NB; ++b) {
            float sx = rdlane(sum[b].x, i);
            float sy = rdlane(sum[b].y, i);
            qk[b].x += sx * w.x + sy * w.z;
            qk[b].y += sx * w.y + sy * w.w;
        }
    }

    // ---- pass C: online softmax over edges, weighted accumulate ----
    float2 acc[NB];
    float mm[NB], ss[NB];
#pragma unroll
    for (int b = 0; b < NB; ++b) {
        acc[b] = make_float2(0.f, 0.f);
        mm[b] = NEG_HUGE;
        ss[b] = 0.f;
    }
#pragma unroll
    for (int b = 0; b < NB; ++b) {
        float2 q = qk[b];
        float qn = qb[b];
        for (int j = s0[b]; j < s1[b]; j += 4) {
            int c = s1[b] - j;
            int e0 = eidx[j];
            int e1 = (c > 1) ? eidx[j + 1] : e0;
            int e2 = (c > 2) ? eidx[j + 2] : e0;
            int e3 = (c > 3) ? eidx[j + 3] : e0;
            float2 r0 = ((const float2*)(msg + (size_t)e0 * D))[lane];
            float2 r1 = ((const float2*)(msg + (size_t)e1 * D))[lane];
            float2 r2 = ((const float2*)(msg + (size_t)e2 * D))[lane];
            float2 r3 = ((const float2*)(msg + (size_t)e3 * D))[lane];
            float p0 = wave_sum(r0.x * q.x + r0.y * q.y);
            float p1 = wave_sum(r1.x * q.x + r1.y * q.y);
            float p2 = wave_sum(r2.x * q.x + r2.y * q.y);
            float p3 = wave_sum(r3.x * q.x + r3.y * q.y);
            float sc0 = (p0 + qn) * RSQRT_D;
            float sc1 = (c > 1) ? (p1 + qn) * RSQRT_D : NEG_HUGE;
            float sc2 = (c > 2) ? (p2 + qn) * RSQRT_D : NEG_HUGE;
            float sc3 = (c > 3) ? (p3 + qn) * RSQRT_D : NEG_HUGE;
            float bm = fmaxf(fmaxf(sc0, sc1), fmaxf(sc2, sc3));
            float nm = fmaxf(mm[b], bm);
            float scale = __expf(mm[b] - nm);
            float w0 = __expf(sc0 - nm);
            float w1 = __expf(sc1 - nm);
            float w2 = __expf(sc2 - nm);
            float w3 = __expf(sc3 - nm);
            ss[b] = ss[b] * scale + ((w0 + w1) + (w2 + w3));
            acc[b].x = acc[b].x * scale + w0 * r0.x + w1 * r1.x + w2 * r2.x + w3 * r3.x;
            acc[b].y = acc[b].y * scale + w0 * r0.y + w1 * r1.y + w2 * r2.y + w3 * r3.y;
            mm[b] = nm;
        }
    }

    // ---- epilogue: out = S @ Wvo + sattn*bvo + bo ----
    float2 S[NB], o[NB];
    float2 bo2 = ((const float2*)bo)[lane];
    float2 bv2 = ((const float2*)bvo)[lane];
#pragma unroll
    for (int b = 0; b < NB; ++b) {
        float inv = 1.f / (ss[b] + 1e-8f);
        S[b].x = acc[b].x * inv;
        S[b].y = acc[b].y * inv;
        float sa = ss[b] * inv;
        o[b].x = bo2.x + sa * bv2.x;
        o[b].y = bo2.y + sa * bv2.y;
    }
    const float4* V4 = (const float4*)Pvo;
#pragma unroll
    for (int i = 0; i < 64; ++i) {
        float4 w = V4[i * 64 + lane];
#pragma unroll
        for (int b = 0; b < NB; ++b) {
            float sx = rdlane(S[b].x, i);
            float sy = rdlane(S[b].y, i);
            o[b].x += sx * w.x + sy * w.z;
            o[b].y += sx * w.y + sy * w.w;
        }
    }
#pragma unroll
    for (int b = 0; b < NB; ++b) {
        int n = n0 + b;
        if (n < N) ((float2*)(out + (size_t)n * D))[lane] = o[b];
    }
}

// ============================ launch ============================

extern "C" void kernel_launch(void* const* d_in, const int* in_sizes, int n_in,
                              void* d_out, int out_size, void* d_ws, size_t ws_size,
                              hipStream_t stream) {
    const float* msg = (const float*)d_in[0];
    const int* recv = (const int*)d_in[1];
    const float* Wk = (const float*)d_in[3];
    const float* bk = (const float*)d_in[4];
    const float* Wv = (const float*)d_in[5];
    const float* bv = (const float*)d_in[6];
    const float* Wq = (const float*)d_in[7];
    const float* bq = (const float*)d_in[8];
    const float* Wo = (const float*)d_in[9];
    const float* bo = (const float*)d_in[10];
    float* out = (float*)d_out;

    int E = in_sizes[0] / D;
    int N = out_size / D;

    char* wsb = (char*)d_ws;
    size_t o = 0;
    auto alloc = [&](size_t elems) { void* p = wsb + o; o += elems * 4; return p; };

    int* cnt    = (int*)alloc(N);
    int* cursor = (int*)alloc(N);      // cnt+cursor adjacent, zeroed together
    int* start  = (int*)alloc(N + 1);
    int* excl   = (int*)alloc(N);
    int* bsum   = (int*)alloc(SCAN_B);
    int* eidx   = (int*)alloc(E);
    float* Pqk  = (float*)alloc(D * D);
    float* bqk  = (float*)alloc(D);
    float* wqb  = (float*)alloc(D);
    float* bqb  = (float*)alloc(1);
    float* Pvo  = (float*)alloc(D * D);
    float* bvo  = (float*)alloc(D);

    hipMemsetAsync(cnt, 0, 2 * (size_t)N * sizeof(int), stream);

    // weight folds (independent of edge data)
    fold_wvo_kernel<<<D + 1, D, 0, stream>>>(Wv, Wo, bv, Pvo, bvo);
    fold_wqk_kernel<<<D + 1, D, 0, stream>>>(Wq, Wk, bq, bk, Pqk, bqk, wqb, bqb);

    // CSR build
    int nbE = (E + 255) / 256;
    int nbS = (N + SCAN_B - 1) / SCAN_B;
    hist_kernel<<<nbE, 256, 0, stream>>>(recv, cnt, E);
    scan1_kernel<<<nbS, SCAN_B, 0, stream>>>(cnt, excl, bsum, N);
    scan2_kernel<<<1, SCAN_B, 0, stream>>>(bsum, nbS);
    scan3_kernel<<<(N + 1 + SCAN_B - 1) / SCAN_B, SCAN_B, 0, stream>>>(excl, bsum, start, N, E);
    fill_kernel<<<nbE, 256, 0, stream>>>(recv, start, cursor, eidx, E);

    // fused: edge-sum -> qk/qb -> online-softmax attention -> output projection
    int wavesNeeded = (N + NB - 1) / NB;
    int blocks = (wavesNeeded + 3) / 4;  // 4 waves per 256-thread block
    fused_kernel<<<blocks, 256, 0, stream>>>(msg, eidx, start, Pqk, bqk, wqb, bqb,
                                             Pvo, bvo, bo, out, N);
}

// Round 4
// 695.055 us; speedup vs baseline: 1.5795x; 1.5795x over previous
//
#include <hip/hip_runtime.h>

#define D 128
#define RSQRT_D 0.088388347648318440550f  // 1/sqrt(128)
#define NEG_HUGE -3.4e38f

#define FMA4(acc, s, b) { acc.x += (s)*(b).x; acc.y += (s)*(b).y; acc.z += (s)*(b).z; acc.w += (s)*(b).w; }

// ---------------- prep: weight folds + zero cnt/cursor ----------------
// blocks 0..63: Wqk/Wvo rows (2 rows per block)
// block 64: bqk/wqb/bvo/bqb
// blocks 65+: zero 2N ints (cnt+cursor)
__global__ __launch_bounds__(256) void prep_kernel(
    const float* __restrict__ Wq, const float* __restrict__ Wk,
    const float* __restrict__ bq, const float* __restrict__ bk,
    const float* __restrict__ Wv, const float* __restrict__ Wo,
    const float* __restrict__ bv,
    float* __restrict__ Wqk, float* __restrict__ bqk,
    float* __restrict__ wqb, float* __restrict__ bqb,
    float* __restrict__ Wvo, float* __restrict__ bvo,
    int* __restrict__ zbase, int zcount) {
    int bid = blockIdx.x, t = threadIdx.x;
    if (bid < 64) {
        int i = bid * 2 + (t >> 7), j = t & 127;
        float a1 = 0.f, a2 = 0.f;
        for (int u = 0; u < D; ++u) {
            a1 += Wq[i * D + u] * Wk[j * D + u];   // (Wq @ Wk^T)[i][j]
            a2 += Wv[i * D + u] * Wo[u * D + j];   // (Wv @ Wo)[i][j]
        }
        Wqk[i * D + j] = a1;
        Wvo[i * D + j] = a2;
    } else if (bid == 64) {
        if (t < D) {
            int j = t;
            float a1 = 0.f, a2 = 0.f, a3 = 0.f;
            for (int u = 0; u < D; ++u) {
                a1 += bq[u] * Wk[j * D + u];       // bq @ Wk^T
                a2 += Wq[j * D + u] * bk[u];       // Wq @ bk
                a3 += bv[u] * Wo[u * D + j];       // bv @ Wo
            }
            bqk[j] = a1; wqb[j] = a2; bvo[j] = a3;
            if (j == 0) {
                float b = 0.f;
                for (int u = 0; u < D; ++u) b += bq[u] * bk[u];
                *bqb = b;
            }
        }
    } else {
        int idx = (bid - 65) * 256 + t;
        if (idx < zcount) zbase[idx] = 0;
    }
}

// ---------------- CSR: histogram ----------------
__global__ void hist_kernel(const int* __restrict__ recv, int* __restrict__ cnt, int E) {
    int e = blockIdx.x * blockDim.x + threadIdx.x;
    if (e >= E) return;
    atomicAdd(&cnt[recv[e]], 1);
}

// ---------------- CSR: single-block exclusive scan of cnt -> start[0..N] ----------------
__global__ __launch_bounds__(1024) void scan_kernel(const int* __restrict__ cnt,
                                                    int* __restrict__ start, int N) {
    __shared__ int wsum[16];
    __shared__ int chunk_total;
    int t = threadIdx.x;
    int w = t >> 6, lane = t & 63;
    int running = 0;
    for (int base = 0; base <= N; base += 1024) {
        int i = base + t;
        int v = (i < N) ? cnt[i] : 0;
        int x = v;
#pragma unroll
        for (int off = 1; off < 64; off <<= 1) {
            int y = __shfl_up(x, off);
            if (lane >= off) x += y;
        }
        if (lane == 63) wsum[w] = x;
        __syncthreads();
        if (w == 0 && lane < 16) {
            int s = wsum[lane];
#pragma unroll
            for (int off = 1; off < 16; off <<= 1) {
                int y = __shfl_up(s, off);
                if (lane >= off) s += y;
            }
            wsum[lane] = s;  // inclusive
            if (lane == 15) chunk_total = s;
        }
        __syncthreads();
        int waveoff = (w == 0) ? 0 : wsum[w - 1];
        if (i <= N) start[i] = running + waveoff + x - v;  // exclusive
        running += chunk_total;
        __syncthreads();
    }
}

// ---------------- CSR: fill edge index lists ----------------
__global__ void fill_kernel(const int* __restrict__ recv, const int* __restrict__ start,
                            int* __restrict__ cursor, int* __restrict__ eidx, int E) {
    int e = blockIdx.x * blockDim.x + threadIdx.x;
    if (e >= E) return;
    int r = recv[e];
    int p = atomicAdd(&cursor[r], 1);
    eidx[start[r] + p] = e;
}

// ---------------- mega: sums -> qk -> online-softmax attn -> out ----------------
// 16 nodes per 256-thread block. Phases hand off through LDS.
__global__ __launch_bounds__(256, 4) void mega_kernel(
    const float* __restrict__ msg, const int* __restrict__ eidx,
    const int* __restrict__ start,
    const float* __restrict__ Wqk, const float* __restrict__ bqk,
    const float* __restrict__ wqb, const float* __restrict__ bqbp,
    const float* __restrict__ Wvo, const float* __restrict__ bvo,
    const float* __restrict__ bo,
    float* __restrict__ out, int N) {
    __shared__ float4 sums4[16 * 32];  // sums, later reused as S
    __shared__ float4 qks4[16 * 32];
    __shared__ float sat[16];
    float* sums = (float*)sums4;

    int t = threadIdx.x;
    int lane = t & 63, w = t >> 6;
    int h = lane >> 5;   // which edge of the pair
    int k = lane & 31;   // float4 feature chunk
    int base = blockIdx.x * 16;
    const float4* msg4 = (const float4*)msg;

    // ---- P1: per-node edge sums (wave w owns nodes base+4w..base+4w+3) ----
    for (int b = 0; b < 4; ++b) {
        int n = base + w * 4 + b;
        int nl = n - base;
        int s0 = 0, s1 = 0;
        if (n < N) { s0 = start[n]; s1 = start[n + 1]; }
        float4 a0 = make_float4(0.f, 0.f, 0.f, 0.f);
        float4 a1 = make_float4(0.f, 0.f, 0.f, 0.f);
        int j = s0;
        for (; j + 4 <= s1; j += 4) {
            int eA = eidx[j + h];
            int eB = eidx[j + 2 + h];
            float4 fA = msg4[(size_t)eA * 32 + k];
            float4 fB = msg4[(size_t)eB * 32 + k];
            a0.x += fA.x; a0.y += fA.y; a0.z += fA.z; a0.w += fA.w;
            a1.x += fB.x; a1.y += fB.y; a1.z += fB.z; a1.w += fB.w;
        }
        for (; j < s1; j += 2) {
            int idx = j + h;
            int e = eidx[idx < s1 ? idx : s1 - 1];
            float4 f = msg4[(size_t)e * 32 + k];
            float mk = (idx < s1) ? 1.f : 0.f;
            a0.x += f.x * mk; a0.y += f.y * mk; a0.z += f.z * mk; a0.w += f.w * mk;
        }
        float4 a = make_float4(a0.x + a1.x, a0.y + a1.y, a0.z + a1.z, a0.w + a1.w);
        a.x += __shfl_xor(a.x, 32);
        a.y += __shfl_xor(a.y, 32);
        a.z += __shfl_xor(a.z, 32);
        a.w += __shfl_xor(a.w, 32);
        if (lane < 32 && n < N) sums4[nl * 32 + k] = a;
    }
    __syncthreads();

    // ---- P2: qk = sums @ Wqk + bqk  (slot handles nodes slot, slot+8) ----
    {
        int c = t & 31, slot = t >> 5;
        const float4* B4 = (const float4*)Wqk;
        float4 acc0 = ((const float4*)bqk)[c];
        float4 acc1 = acc0;
        for (int i = 0; i < D; i += 4) {
            float4 aA = sums4[slot * 32 + (i >> 2)];
            float4 aB = sums4[(slot + 8) * 32 + (i >> 2)];
            float4 b0 = B4[(i + 0) * 32 + c];
            float4 b1 = B4[(i + 1) * 32 + c];
            float4 b2 = B4[(i + 2) * 32 + c];
            float4 b3 = B4[(i + 3) * 32 + c];
            FMA4(acc0, aA.x, b0); FMA4(acc0, aA.y, b1); FMA4(acc0, aA.z, b2); FMA4(acc0, aA.w, b3);
            FMA4(acc1, aB.x, b0); FMA4(acc1, aB.y, b1); FMA4(acc1, aB.z, b2); FMA4(acc1, aB.w, b3);
        }
        qks4[slot * 32 + c] = acc0;
        qks4[(slot + 8) * 32 + c] = acc1;
    }
    __syncthreads();

    // ---- P3: online-softmax attention (wave w owns its 4 nodes) ----
    float bqb = bqbp[0];
    for (int b = 0; b < 4; ++b) {
        int n = base + w * 4 + b;
        if (n >= N) break;
        int nl = n - base;
        int s0 = start[n], s1 = start[n + 1];
        float4 q = qks4[nl * 32 + k];
        // qb = dot(sums[nl], wqb) + bqb  (sums still valid for this node)
        float4 sv = sums4[nl * 32 + k];
        float4 wv = ((const float4*)wqb)[k];
        float pq = sv.x * wv.x + sv.y * wv.y + sv.z * wv.z + sv.w * wv.w;
        pq += __shfl_xor(pq, 1); pq += __shfl_xor(pq, 2); pq += __shfl_xor(pq, 4);
        pq += __shfl_xor(pq, 8); pq += __shfl_xor(pq, 16);
        float qb = pq + bqb;

        float m = NEG_HUGE, s = 0.f;
        float4 acc = make_float4(0.f, 0.f, 0.f, 0.f);
        int j = s0;
        float4 fC = make_float4(0.f, 0.f, 0.f, 0.f);
        if (j < s1) {
            int idx = j + h;
            int e = eidx[idx < s1 ? idx : s1 - 1];
            fC = msg4[(size_t)e * 32 + k];
        }
        while (j < s1) {
            int jn = j + 2;
            float4 fN = make_float4(0.f, 0.f, 0.f, 0.f);
            if (jn < s1) {
                int idx = jn + h;
                int e = eidx[idx < s1 ? idx : s1 - 1];
                fN = msg4[(size_t)e * 32 + k];
            }
            int valid = (j + h) < s1;
            float p = fC.x * q.x + fC.y * q.y + fC.z * q.z + fC.w * q.w;
            p += __shfl_xor(p, 1); p += __shfl_xor(p, 2); p += __shfl_xor(p, 4);
            p += __shfl_xor(p, 8); p += __shfl_xor(p, 16);
            float sc = valid ? (p + qb) * RSQRT_D : NEG_HUGE;
            float nm = fmaxf(m, sc);
            float scale = __expf(m - nm);
            float ww = __expf(sc - nm);
            s = s * scale + ww;
            acc.x = acc.x * scale + ww * fC.x;
            acc.y = acc.y * scale + ww * fC.y;
            acc.z = acc.z * scale + ww * fC.z;
            acc.w = acc.w * scale + ww * fC.w;
            m = nm;
            fC = fN;
            j = jn;
        }
        // merge the two half-wave softmax states (phantom halves get weight 0)
        float mo = __shfl_xor(m, 32);
        float so = __shfl_xor(s, 32);
        float4 ao;
        ao.x = __shfl_xor(acc.x, 32); ao.y = __shfl_xor(acc.y, 32);
        ao.z = __shfl_xor(acc.z, 32); ao.w = __shfl_xor(acc.w, 32);
        float mt = fmaxf(m, mo);
        float c0 = __expf(m - mt), c1 = __expf(mo - mt);
        float st = s * c0 + so * c1;
        float4 aT;
        aT.x = acc.x * c0 + ao.x * c1;
        aT.y = acc.y * c0 + ao.y * c1;
        aT.z = acc.z * c0 + ao.z * c1;
        aT.w = acc.w * c0 + ao.w * c1;
        float inv = 1.f / (st + 1e-8f);
        if (lane < 32)
            sums4[nl * 32 + k] = make_float4(aT.x * inv, aT.y * inv, aT.z * inv, aT.w * inv);
        if (lane == 0) sat[nl] = st * inv;  // sum of attn weights
    }
    __syncthreads();

    // ---- P4: out = S @ Wvo + sat*bvo + bo ----
    {
        int c = t & 31, slot = t >> 5;
        const float4* B4 = (const float4*)Wvo;
        float4 bo4 = ((const float4*)bo)[c];
        float4 bv4 = ((const float4*)bvo)[c];
        float sa0 = sat[slot], sa1 = sat[slot + 8];
        float4 acc0 = make_float4(bo4.x + sa0 * bv4.x, bo4.y + sa0 * bv4.y,
                                  bo4.z + sa0 * bv4.z, bo4.w + sa0 * bv4.w);
        float4 acc1 = make_float4(bo4.x + sa1 * bv4.x, bo4.y + sa1 * bv4.y,
                                  bo4.z + sa1 * bv4.z, bo4.w + sa1 * bv4.w);
        for (int i = 0; i < D; i += 4) {
            float4 aA = sums4[slot * 32 + (i >> 2)];
            float4 aB = sums4[(slot + 8) * 32 + (i >> 2)];
            float4 b0 = B4[(i + 0) * 32 + c];
            float4 b1 = B4[(i + 1) * 32 + c];
            float4 b2 = B4[(i + 2) * 32 + c];
            float4 b3 = B4[(i + 3) * 32 + c];
            FMA4(acc0, aA.x, b0); FMA4(acc0, aA.y, b1); FMA4(acc0, aA.z, b2); FMA4(acc0, aA.w, b3);
            FMA4(acc1, aB.x, b0); FMA4(acc1, aB.y, b1); FMA4(acc1, aB.z, b2); FMA4(acc1, aB.w, b3);
        }
        int n0 = base + slot, n1 = base + slot + 8;
        if (n0 < N) ((float4*)(out + (size_t)n0 * D))[c] = acc0;
        if (n1 < N) ((float4*)(out + (size_t)n1 * D))[c] = acc1;
    }
}

// ============================ launch ============================

extern "C" void kernel_launch(void* const* d_in, const int* in_sizes, int n_in,
                              void* d_out, int out_size, void* d_ws, size_t ws_size,
                              hipStream_t stream) {
    const float* msg = (const float*)d_in[0];
    const int* recv = (const int*)d_in[1];
    const float* Wk = (const float*)d_in[3];
    const float* bk = (const float*)d_in[4];
    const float* Wv = (const float*)d_in[5];
    const float* bv = (const float*)d_in[6];
    const float* Wq = (const float*)d_in[7];
    const float* bq = (const float*)d_in[8];
    const float* Wo = (const float*)d_in[9];
    const float* bo = (const float*)d_in[10];
    float* out = (float*)d_out;

    int E = in_sizes[0] / D;
    int N = out_size / D;

    char* wsb = (char*)d_ws;
    size_t o = 0;
    auto alloc = [&](size_t elems) { void* p = wsb + o; o += elems * 4; return p; };

    int* cnt    = (int*)alloc(N);
    int* cursor = (int*)alloc(N);      // cnt+cursor contiguous: zeroed by prep
    int* start  = (int*)alloc(N + 1);
    int* eidx   = (int*)alloc(E);
    float* Wqk  = (float*)alloc(D * D);
    float* bqk  = (float*)alloc(D);
    float* wqb  = (float*)alloc(D);
    float* bqb  = (float*)alloc(1);
    float* Wvo  = (float*)alloc(D * D);
    float* bvo  = (float*)alloc(D);

    int zcount = 2 * N;
    int zblocks = (zcount + 255) / 256;
    prep_kernel<<<65 + zblocks, 256, 0, stream>>>(Wq, Wk, bq, bk, Wv, Wo, bv,
                                                  Wqk, bqk, wqb, bqb, Wvo, bvo,
                                                  cnt, zcount);
    int nbE = (E + 255) / 256;
    hist_kernel<<<nbE, 256, 0, stream>>>(recv, cnt, E);
    scan_kernel<<<1, 1024, 0, stream>>>(cnt, start, N);
    fill_kernel<<<nbE, 256, 0, stream>>>(recv, start, cursor, eidx, E);
    mega_kernel<<<(N + 15) / 16, 256, 0, stream>>>(msg, eidx, start, Wqk, bqk, wqb, bqb,
                                                   Wvo, bvo, bo, out, N);
}